// Round 7
// baseline (430.339 us; speedup 1.0000x reference)
//
#include <hip/hip_runtime.h>
#include <math.h>

// DigitCaps dynamic routing. B=512, I=1152, K=8, C=10, D=16, 3 iters.
//
// R5 structure: materialize bf16 u_hat (189 MB) in ws; each routing pass
// streams it once; softmax fully in-register.
// R7 POST-MORTEM: forcing launch_bounds down -> allocator spills. Keep (256,4).
// R9/R10/R12 POST-MORTEMS: (a) one uniform dispatch round per kernel; ragged
//   (1.5x) rounds cost ~50%. (b) extra i-chunks double s0 atomics (+30us).
//   (c) b-pairs double W_t load work: TLP gain < added loads (143->168).
//   Producer best-known = b-QUAD, K1_CH 32, grid 1024, VGPR 64: 143us.
// R11 POST-MORTEM: source-level ILP (prefetch rotate / 2-chain) compiled away
//   or gained ~3us. Compiler defeats manual pipelining.
// R13 (this round): route is TLP-responsive (VGPR-20 original did 75us at 6
//   waves/SIMD with 6x the shuffles; c-lane layouts at 4 waves/SIMD do 82-85).
//   -> route5: register-lean c-lane route. No x[16] staging (unpack bf16 words
//   twice: +16 VALU/step, -16 VGPR), single-step prefetch, target natural
//   VGPR <=64 -> 8 waves/SIMD; grid 2048 (K2_CH 16, 72 i/wave). Route waves
//   partition u_hat, so doubling waves adds NO redundant traffic.
//   Downside bounded: VGPR>64 -> exactly 2 uniform rounds ~= current 82us.

#define UHQ 40          // ushort4 quads per (b,i) row (160 bf16 elems)
#define K1_CH 32        // producer i-chunks (36 i each), 4 b per wave
#define K2_CH 16        // route i-chunks per b (72 i each)

__device__ __forceinline__ float dot8(const float4 w0, const float4 w1,
                                      const float4 ua, const float4 ub) {
    return w0.x*ua.x + w0.y*ua.y + w0.z*ua.z + w0.w*ua.w
         + w1.x*ub.x + w1.y*ub.y + w1.z*ub.z + w1.w*ub.w;
}

__device__ __forceinline__ unsigned short bf16_rn(float x) {
    unsigned u = __float_as_uint(x);
    u += 0x7FFFu + ((u >> 16) & 1u);
    return (unsigned short)(u >> 16);
}
__device__ __forceinline__ float bf16_lo(unsigned p) {   // low bf16 of packed pair
    return __uint_as_float(p << 16);
}
__device__ __forceinline__ float bf16_hi(unsigned p) {   // high bf16 of packed pair
    return __uint_as_float(p & 0xFFFF0000u);
}

// ---------------- W transpose: W[i][c][d][k] -> W_t[i][j][q] (float4 units) ----------------
__global__ void transpose_W(const float4* __restrict__ W4, float4* __restrict__ Wt4)
{
    int tid = blockIdx.x * 256 + threadIdx.x;
    if (tid >= 1152 * 320) return;
    int i = tid / 320, r = tid - i * 320;
    int q = r >> 3, j = r & 7;
    Wt4[i * 320 + j * 40 + q] = W4[tid];   // read coalesced, scatter within 5 KB row
}

// ---------------- Producer (coalesced W_t): u_hat bf16 + fused pass-0 sum ----------------
// EXACT R11 config: b-quad, K1_CH 32 (36 i), grid 1024, VGPR 64. 143us known.
__global__ __launch_bounds__(256, 4)
void produce_uhat_t(const float* __restrict__ u, const float* __restrict__ Wt,
                    unsigned short* __restrict__ uhat_h, float* __restrict__ s0)
{
    const int t = threadIdx.x, lane = t & 63, wv = t >> 6;
    const int gid = blockIdx.x * 4 + wv;
    const int bq  = gid / K1_CH;          // 0..127
    const int ch  = gid - bq * K1_CH;     // 0..31
    const int b0  = bq * 4;
    const int i0  = ch * 36;
    const int q   = lane;
    const bool act = (q < UHQ);

    float4 acc[4];
    #pragma unroll
    for (int bb = 0; bb < 4; ++bb) acc[bb] = make_float4(0.f, 0.f, 0.f, 0.f);

    for (int ii = 0; ii < 36; ++ii) {
        const int i = i0 + ii;
        float4 w4[8];
        if (act) {
            const float4* wb = (const float4*)(Wt + (size_t)i * 1280);
            #pragma unroll
            for (int j = 0; j < 8; ++j) w4[j] = wb[j * 40 + q];   // 640 B contiguous
        }
        #pragma unroll
        for (int bb = 0; bb < 4; ++bb) {
            const int b = b0 + bb;
            const float4* up = (const float4*)(u + ((size_t)b * 1152 + i) * 8);
            const float4 ua = up[0], ub = up[1];   // wave-uniform broadcast
            if (act) {
                float4 uh;
                uh.x = dot8(w4[0], w4[1], ua, ub);
                uh.y = dot8(w4[2], w4[3], ua, ub);
                uh.z = dot8(w4[4], w4[5], ua, ub);
                uh.w = dot8(w4[6], w4[7], ua, ub);
                acc[bb].x += uh.x; acc[bb].y += uh.y;
                acc[bb].z += uh.z; acc[bb].w += uh.w;
                ushort4 h;
                h.x = bf16_rn(uh.x); h.y = bf16_rn(uh.y);
                h.z = bf16_rn(uh.z); h.w = bf16_rn(uh.w);
                ((ushort4*)uhat_h)[((size_t)b * 1152 + i) * UHQ + q] = h;
            }
        }
    }
    if (act) {
#if defined(__HIP_DEVICE_COMPILE__)
        #pragma unroll
        for (int bb = 0; bb < 4; ++bb) {
            float* sp = s0 + (size_t)(b0 + bb) * 160 + q * 4;
            unsafeAtomicAdd(sp + 0, acc[bb].x);
            unsafeAtomicAdd(sp + 1, acc[bb].y);
            unsafeAtomicAdd(sp + 2, acc[bb].z);
            unsafeAtomicAdd(sp + 3, acc[bb].w);
        }
#endif
    }
}

// ---------------- Producer fallback (divergent W, no W_t buffer) ----------------
__global__ __launch_bounds__(256, 4)
void produce_uhat_div(const float* __restrict__ u, const float* __restrict__ W,
                      unsigned short* __restrict__ uhat_h, float* __restrict__ s0)
{
    const int t = threadIdx.x, lane = t & 63, wv = t >> 6;
    const int gid = blockIdx.x * 4 + wv;
    const int bq  = gid / K1_CH;
    const int ch  = gid - bq * K1_CH;
    const int b0  = bq * 4;
    const int i0  = ch * 36;
    const int q   = lane;
    const bool act = (q < UHQ);

    float4 acc[4];
    #pragma unroll
    for (int bb = 0; bb < 4; ++bb) acc[bb] = make_float4(0.f, 0.f, 0.f, 0.f);

    for (int ii = 0; ii < 36; ++ii) {
        const int i = i0 + ii;
        float4 w4[8];
        if (act) {
            const float4* wp = (const float4*)(W + (size_t)i * 1280 + q * 32);
            #pragma unroll
            for (int j = 0; j < 8; ++j) w4[j] = wp[j];
        }
        #pragma unroll
        for (int bb = 0; bb < 4; ++bb) {
            const int b = b0 + bb;
            const float4* up = (const float4*)(u + ((size_t)b * 1152 + i) * 8);
            const float4 ua = up[0], ub = up[1];
            if (act) {
                float4 uh;
                uh.x = dot8(w4[0], w4[1], ua, ub);
                uh.y = dot8(w4[2], w4[3], ua, ub);
                uh.z = dot8(w4[4], w4[5], ua, ub);
                uh.w = dot8(w4[6], w4[7], ua, ub);
                acc[bb].x += uh.x; acc[bb].y += uh.y;
                acc[bb].z += uh.z; acc[bb].w += uh.w;
                ushort4 h;
                h.x = bf16_rn(uh.x); h.y = bf16_rn(uh.y);
                h.z = bf16_rn(uh.z); h.w = bf16_rn(uh.w);
                ((ushort4*)uhat_h)[((size_t)b * 1152 + i) * UHQ + q] = h;
            }
        }
    }
    if (act) {
#if defined(__HIP_DEVICE_COMPILE__)
        #pragma unroll
        for (int bb = 0; bb < 4; ++bb) {
            float* sp = s0 + (size_t)(b0 + bb) * 160 + q * 4;
            unsafeAtomicAdd(sp + 0, acc[bb].x);
            unsafeAtomicAdd(sp + 1, acc[bb].y);
            unsafeAtomicAdd(sp + 2, acc[bb].z);
            unsafeAtomicAdd(sp + 3, acc[bb].w);
        }
#endif
    }
}

// ---------------- Routing pass v5: register-lean c-lane layout, 8 waves/SIMD ----------------
// lane = (i_sub 0..3, c 0..15); wave does 4 rows/step, 72 i (18 steps).
// No x[16] staging: bf16 words unpacked inline in the dot AND in the
// accumulate (+16 VALU/step, -16 VGPR). Single-step prefetch. Target natural
// VGPR <=64 -> 8 waves/SIMD. launch_bounds stays (256,4) - never force.
template <int PASS>
__global__ __launch_bounds__(256, 4)
void route5(const unsigned short* __restrict__ uhat_h,
            const float* __restrict__ v0g, const float* __restrict__ v1g,
            float* __restrict__ sg)
{
    const int t = threadIdx.x, lane = t & 63, wv = t >> 6;
    const int gid  = blockIdx.x * 4 + wv;
    const int b    = gid >> 4;            // 0..511
    const int ch   = gid & 15;            // 0..15
    const int i0   = ch * 72;
    const int isub = lane >> 4;           // 0..3
    const int c    = lane & 15;           // 0..15, valid c<10
    const bool act = (c < 10);
    const int cc   = act ? c : 9;         // clamp for v load

    // v[b, cc, 0..15]  (f32)
    float v[16];
    {
        const float4* vp = (const float4*)(v0g + ((size_t)b * 10 + cc) * 16);
        float4 a0 = vp[0], a1 = vp[1], a2 = vp[2], a3 = vp[3];
        if (PASS == 2) {
            const float4* vq = (const float4*)(v1g + ((size_t)b * 10 + cc) * 16);
            float4 b0 = vq[0], b1 = vq[1], b2 = vq[2], b3 = vq[3];
            a0.x += b0.x; a0.y += b0.y; a0.z += b0.z; a0.w += b0.w;
            a1.x += b1.x; a1.y += b1.y; a1.z += b1.z; a1.w += b1.w;
            a2.x += b2.x; a2.y += b2.y; a2.z += b2.z; a2.w += b2.w;
            a3.x += b3.x; a3.y += b3.y; a3.z += b3.z; a3.w += b3.w;
        }
        v[0]=a0.x; v[1]=a0.y; v[2]=a0.z; v[3]=a0.w;
        v[4]=a1.x; v[5]=a1.y; v[6]=a1.z; v[7]=a1.w;
        v[8]=a2.x; v[9]=a2.y; v[10]=a2.z; v[11]=a2.w;
        v[12]=a3.x; v[13]=a3.y; v[14]=a3.z; v[15]=a3.w;
    }

    float sacc[16];
    #pragma unroll
    for (int d = 0; d < 16; ++d) sacc[d] = 0.0f;

    const uint4* up = (const uint4*)uhat_h;   // 8 bf16 per uint4
    // row (b,i) = 160 bf16 = 20 uint4; lane slice +c*2; step stride = 80 uint4
    size_t base = ((size_t)b * 1152 + i0 + isub) * 20 + (size_t)c * 2;

    uint4 h0 = make_uint4(0u,0u,0u,0u), h1 = h0;
    if (act) { h0 = up[base]; h1 = up[base + 1]; }

    #pragma unroll 1
    for (int tt = 0; tt < 18; ++tt) {
        // prefetch next step before consuming current
        uint4 n0 = make_uint4(0u,0u,0u,0u), n1 = n0;
        if (act && (tt + 1 < 18)) { n0 = up[base + 80]; n1 = up[base + 81]; }
        base += 80;

        // lane-local dot over d, unpack inline (4 partial chains)
        float d0 = bf16_lo(h0.x)*v[0] + bf16_lo(h0.z)*v[4]
                 + bf16_lo(h1.x)*v[8] + bf16_lo(h1.z)*v[12];
        float d1 = bf16_hi(h0.x)*v[1] + bf16_hi(h0.z)*v[5]
                 + bf16_hi(h1.x)*v[9] + bf16_hi(h1.z)*v[13];
        float d2 = bf16_lo(h0.y)*v[2] + bf16_lo(h0.w)*v[6]
                 + bf16_lo(h1.y)*v[10] + bf16_lo(h1.w)*v[14];
        float d3 = bf16_hi(h0.y)*v[3] + bf16_hi(h0.w)*v[7]
                 + bf16_hi(h1.y)*v[11] + bf16_hi(h1.w)*v[15];
        const float logit = (d0 + d1) + (d2 + d3);
        // softmax over c inside the 16-lane group (no max-sub: |logit| small)
        const float e = act ? __expf(logit) : 0.0f;
        float ss = e;
        ss += __shfl_xor(ss, 1);
        ss += __shfl_xor(ss, 2);
        ss += __shfl_xor(ss, 4);
        ss += __shfl_xor(ss, 8);
        const float coef = e * __builtin_amdgcn_rcpf(ss);
        // accumulate, unpacking again (registers die immediately)
        sacc[0]  += coef * bf16_lo(h0.x);  sacc[1]  += coef * bf16_hi(h0.x);
        sacc[2]  += coef * bf16_lo(h0.y);  sacc[3]  += coef * bf16_hi(h0.y);
        sacc[4]  += coef * bf16_lo(h0.z);  sacc[5]  += coef * bf16_hi(h0.z);
        sacc[6]  += coef * bf16_lo(h0.w);  sacc[7]  += coef * bf16_hi(h0.w);
        sacc[8]  += coef * bf16_lo(h1.x);  sacc[9]  += coef * bf16_hi(h1.x);
        sacc[10] += coef * bf16_lo(h1.y);  sacc[11] += coef * bf16_hi(h1.y);
        sacc[12] += coef * bf16_lo(h1.z);  sacc[13] += coef * bf16_hi(h1.z);
        sacc[14] += coef * bf16_lo(h1.w);  sacc[15] += coef * bf16_hi(h1.w);

        h0 = n0; h1 = n1;
    }

    // reduce over the 4 i_sub groups: lanes {L, L^16, L^32, L^48}
    #pragma unroll
    for (int d = 0; d < 16; ++d) {
        sacc[d] += __shfl_xor(sacc[d], 16);
        sacc[d] += __shfl_xor(sacc[d], 32);
    }
    if (lane < 10) {
#if defined(__HIP_DEVICE_COMPILE__)
        float* sp = sg + (size_t)b * 160 + c * 16;
        #pragma unroll
        for (int d = 0; d < 16; ++d) unsafeAtomicAdd(sp + d, sacc[d]);
#endif
    }
}

// ---------------- squash with pre-scale ----------------
__global__ void squash_scale(const float* __restrict__ s, float* __restrict__ vout,
                             float scale)
{
    int r = blockIdx.x * 256 + threadIdx.x;
    if (r >= 512 * 10) return;
    const float* sp = s + (size_t)r * 16;
    float sv[16];
    float ns = 0.0f;
    #pragma unroll
    for (int d = 0; d < 16; ++d) {
        float x = sp[d] * scale;
        sv[d] = x;
        ns += x * x;
    }
    float sc = ns / ((1.0f + ns) * (sqrtf(ns) + 1e-8f));
    float* o = vout + (size_t)r * 16;
    #pragma unroll
    for (int d = 0; d < 16; ++d) o[d] = sv[d] * sc;
}

// ---------------- tiny-ws fallback (R3-style): thread owns (b,c) ----------------
template <int PASS>
__global__ __launch_bounds__(256, 4)
void pass_fb(const float* __restrict__ u, const float* __restrict__ W,
             const float* __restrict__ v0g, const float* __restrict__ v1g,
             float* __restrict__ s_atomic)
{
    const int t    = threadIdx.x;
    const int lane = t & 63;
    const int wv   = t >> 6;
    const int bsub = lane / 10;
    const int c    = lane - bsub * 10;
    const bool lane_ok = (bsub < 6);
    const int b    = blockIdx.y * 24 + wv * 6 + bsub;
    const bool valid = lane_ok && (b < 512);
    const int bc   = valid ? b : 511;
    const int base = lane_ok ? bsub * 10 : 0;
    const int i0   = blockIdx.x * 24;

    float v[16];
    #pragma unroll
    for (int d = 0; d < 16; ++d) v[d] = 0.0f;
    if (PASS >= 1) {
        const float* vp = v0g + ((size_t)bc * 10 + c) * 16;
        #pragma unroll
        for (int d = 0; d < 16; ++d) v[d] = vp[d];
        if (PASS >= 2) {
            const float* vq = v1g + ((size_t)bc * 10 + c) * 16;
            #pragma unroll
            for (int d = 0; d < 16; ++d) v[d] += vq[d];
        }
    }

    float s_acc[16];
    #pragma unroll
    for (int d = 0; d < 16; ++d) s_acc[d] = 0.0f;

    for (int ii = 0; ii < 24; ++ii) {
        const int i = i0 + ii;
        const float4* up = (const float4*)(u + ((size_t)bc * 1152 + i) * 8);
        const float4 ua = up[0];
        const float4 ub = up[1];
        const float* Wp = W + ((size_t)i * 10 + c) * 128;

        float h[16];
        #pragma unroll
        for (int d = 0; d < 16; ++d) {
            const float4* wp = (const float4*)(Wp + d * 8);
            h[d] = dot8(wp[0], wp[1], ua, ub);
        }

        if (PASS == 0) {
            #pragma unroll
            for (int d = 0; d < 16; ++d) s_acc[d] += h[d];
        } else {
            float lg = 0.0f;
            #pragma unroll
            for (int d = 0; d < 16; ++d) lg += h[d] * v[d];
            float lj[10];
            #pragma unroll
            for (int j = 0; j < 10; ++j) lj[j] = __shfl(lg, base + j);
            float m = lj[0];
            #pragma unroll
            for (int j = 1; j < 10; ++j) m = fmaxf(m, lj[j]);
            float sum = 0.0f;
            #pragma unroll
            for (int j = 0; j < 10; ++j) sum += __expf(lj[j] - m);
            const float coef = __expf(lg - m) / sum;
            #pragma unroll
            for (int d = 0; d < 16; ++d) s_acc[d] += coef * h[d];
        }
    }
    if (PASS == 0) {
        #pragma unroll
        for (int d = 0; d < 16; ++d) s_acc[d] *= 0.1f;
    }
    if (valid) {
#if defined(__HIP_DEVICE_COMPILE__)
        #pragma unroll
        for (int d = 0; d < 16; ++d)
            unsafeAtomicAdd(&s_atomic[((size_t)b * 10 + c) * 16 + d], s_acc[d]);
#endif
    }
}

extern "C" void kernel_launch(void* const* d_in, const int* in_sizes, int n_in,
                              void* d_out, int out_size, void* d_ws, size_t ws_size,
                              hipStream_t stream)
{
    const float* u = (const float*)d_in[0];   // [512,1152,8]
    const float* W = (const float*)d_in[1];   // [1152,10,16,8]
    float* out = (float*)d_out;               // [512,10,16]

    float* v0 = (float*)d_ws;
    float* v1 = v0 + 81920;
    float* s0 = v1 + 81920;
    float* s1 = s0 + 81920;
    float* s2 = s1 + 81920;
    float* wt = s2 + 81920;                   // 1,474,560 f32 (5.9 MB)

    const size_t head   = (size_t)5 * 81920 * sizeof(float);          // 1.64 MB
    const size_t wtsz   = (size_t)1152 * 1280 * sizeof(float);        // 5.90 MB
    const size_t uh_b16 = (size_t)512 * 1152 * 160 * 2;               // 188.7 MB

    hipMemsetAsync(s0, 0, (size_t)3 * 81920 * sizeof(float), stream);

    dim3 blk(256);

    if (ws_size >= head + wtsz + uh_b16) {
        unsigned short* uhh = (unsigned short*)(wt + 1152 * 1280);
        transpose_W<<<1440, blk, 0, stream>>>((const float4*)W, (float4*)wt);
        produce_uhat_t<<<1024, blk, 0, stream>>>(u, wt, uhh, s0);
        squash_scale<<<20, blk, 0, stream>>>(s0, v0, 0.1f);
        route5<1><<<2048, blk, 0, stream>>>(uhh, v0, nullptr, s1);
        squash_scale<<<20, blk, 0, stream>>>(s1, v1, 1.0f);
        route5<2><<<2048, blk, 0, stream>>>(uhh, v0, v1, s2);
        squash_scale<<<20, blk, 0, stream>>>(s2, out, 1.0f);
    } else if (ws_size >= head + uh_b16) {
        unsigned short* uhh = (unsigned short*)wt;   // no W_t buffer
        produce_uhat_div<<<1024, blk, 0, stream>>>(u, W, uhh, s0);
        squash_scale<<<20, blk, 0, stream>>>(s0, v0, 0.1f);
        route5<1><<<2048, blk, 0, stream>>>(uhh, v0, nullptr, s1);
        squash_scale<<<20, blk, 0, stream>>>(s1, v1, 1.0f);
        route5<2><<<2048, blk, 0, stream>>>(uhh, v0, v1, s2);
        squash_scale<<<20, blk, 0, stream>>>(s2, out, 1.0f);
    } else {
        dim3 grid(48, 22);
        pass_fb<0><<<grid, blk, 0, stream>>>(u, W, nullptr, nullptr, s0);
        squash_scale<<<20, blk, 0, stream>>>(s0, v0, 1.0f);
        pass_fb<1><<<grid, blk, 0, stream>>>(u, W, v0, nullptr, s1);
        squash_scale<<<20, blk, 0, stream>>>(s1, v1, 1.0f);
        pass_fb<2><<<grid, blk, 0, stream>>>(u, W, v0, v1, s2);
        squash_scale<<<20, blk, 0, stream>>>(s2, out, 1.0f);
    }
}

// Round 8
// 310.910 us; speedup vs baseline: 1.3841x; 1.3841x over previous
//
#include <hip/hip_runtime.h>
#include <math.h>

// DigitCaps dynamic routing. B=512, I=1152, K=8, C=10, D=16, 3 iters.
//
// R5 structure: materialize bf16 u_hat (189 MB) in ws; each routing pass
// streams it once; softmax fully in-register.
// R7 POST-MORTEM: forcing launch_bounds below natural need -> spills. 
// R9/R10/R12: one uniform dispatch round per kernel; extra i-chunks double
//   s0 atomics; b-pairs double W_t loads. Producer best = b-QUAD, K1_CH 32,
//   grid 1024, VGPR 64: 143us.
// R11: source-level ILP gets compiled away (~0-3us).
// R13 POST-MORTEM: route5 (c-lane + double-unpack) regressed to 130us/pass --
//   never reached the 64-VGPR tier, added VALU. The c-lane family (v[16]+
//   sacc[16] >= 80 VGPR) is stuck at 4 waves/SIMD = 82-130us. The ORIGINAL
//   cd-quad route_pass (VGPR 20!) did 75us at only 6 ragged blocks/CU.
//   Route is TLP-responsive (waves partition u_hat: no redundant traffic).
// R14: revive round-0 route_pass verbatim with exactly two deltas:
//   (1) grid 2048 (K2_CH 16, 72 i/wave) -> 8 blocks/CU, uniform full round;
//   (2) rcp instead of IEEE divide (validated in route4, same absmax).

#define UHQ 40          // ushort4 quads per (b,i) row (160 bf16 elems)
#define K1_CH 32        // producer i-chunks (36 i each), 4 b per wave
#define K2_CH 16        // route i-chunks per b (72 i each)

__device__ __forceinline__ float dot8(const float4 w0, const float4 w1,
                                      const float4 ua, const float4 ub) {
    return w0.x*ua.x + w0.y*ua.y + w0.z*ua.z + w0.w*ua.w
         + w1.x*ub.x + w1.y*ub.y + w1.z*ub.z + w1.w*ub.w;
}

__device__ __forceinline__ unsigned short bf16_rn(float x) {
    unsigned u = __float_as_uint(x);
    u += 0x7FFFu + ((u >> 16) & 1u);
    return (unsigned short)(u >> 16);
}
__device__ __forceinline__ float bf16_to_f(unsigned short h) {
    return __uint_as_float(((unsigned)h) << 16);
}

// ---------------- W transpose: W[i][c][d][k] -> W_t[i][j][q] (float4 units) ----------------
__global__ void transpose_W(const float4* __restrict__ W4, float4* __restrict__ Wt4)
{
    int tid = blockIdx.x * 256 + threadIdx.x;
    if (tid >= 1152 * 320) return;
    int i = tid / 320, r = tid - i * 320;
    int q = r >> 3, j = r & 7;
    Wt4[i * 320 + j * 40 + q] = W4[tid];   // read coalesced, scatter within 5 KB row
}

// ---------------- Producer (coalesced W_t): u_hat bf16 + fused pass-0 sum ----------------
// R13 config (best known): b-quad, K1_CH 32 (36 i), grid 1024, VGPR 64. 143us.
__global__ __launch_bounds__(256, 4)
void produce_uhat_t(const float* __restrict__ u, const float* __restrict__ Wt,
                    unsigned short* __restrict__ uhat_h, float* __restrict__ s0)
{
    const int t = threadIdx.x, lane = t & 63, wv = t >> 6;
    const int gid = blockIdx.x * 4 + wv;
    const int bq  = gid / K1_CH;          // 0..127
    const int ch  = gid - bq * K1_CH;     // 0..31
    const int b0  = bq * 4;
    const int i0  = ch * 36;
    const int q   = lane;
    const bool act = (q < UHQ);

    float4 acc[4];
    #pragma unroll
    for (int bb = 0; bb < 4; ++bb) acc[bb] = make_float4(0.f, 0.f, 0.f, 0.f);

    for (int ii = 0; ii < 36; ++ii) {
        const int i = i0 + ii;
        float4 w4[8];
        if (act) {
            const float4* wb = (const float4*)(Wt + (size_t)i * 1280);
            #pragma unroll
            for (int j = 0; j < 8; ++j) w4[j] = wb[j * 40 + q];   // 640 B contiguous
        }
        #pragma unroll
        for (int bb = 0; bb < 4; ++bb) {
            const int b = b0 + bb;
            const float4* up = (const float4*)(u + ((size_t)b * 1152 + i) * 8);
            const float4 ua = up[0], ub = up[1];   // wave-uniform broadcast
            if (act) {
                float4 uh;
                uh.x = dot8(w4[0], w4[1], ua, ub);
                uh.y = dot8(w4[2], w4[3], ua, ub);
                uh.z = dot8(w4[4], w4[5], ua, ub);
                uh.w = dot8(w4[6], w4[7], ua, ub);
                acc[bb].x += uh.x; acc[bb].y += uh.y;
                acc[bb].z += uh.z; acc[bb].w += uh.w;
                ushort4 h;
                h.x = bf16_rn(uh.x); h.y = bf16_rn(uh.y);
                h.z = bf16_rn(uh.z); h.w = bf16_rn(uh.w);
                ((ushort4*)uhat_h)[((size_t)b * 1152 + i) * UHQ + q] = h;
            }
        }
    }
    if (act) {
#if defined(__HIP_DEVICE_COMPILE__)
        #pragma unroll
        for (int bb = 0; bb < 4; ++bb) {
            float* sp = s0 + (size_t)(b0 + bb) * 160 + q * 4;
            unsafeAtomicAdd(sp + 0, acc[bb].x);
            unsafeAtomicAdd(sp + 1, acc[bb].y);
            unsafeAtomicAdd(sp + 2, acc[bb].z);
            unsafeAtomicAdd(sp + 3, acc[bb].w);
        }
#endif
    }
}

// ---------------- Producer fallback (divergent W, no W_t buffer) ----------------
__global__ __launch_bounds__(256, 4)
void produce_uhat_div(const float* __restrict__ u, const float* __restrict__ W,
                      unsigned short* __restrict__ uhat_h, float* __restrict__ s0)
{
    const int t = threadIdx.x, lane = t & 63, wv = t >> 6;
    const int gid = blockIdx.x * 4 + wv;
    const int bq  = gid / K1_CH;
    const int ch  = gid - bq * K1_CH;
    const int b0  = bq * 4;
    const int i0  = ch * 36;
    const int q   = lane;
    const bool act = (q < UHQ);

    float4 acc[4];
    #pragma unroll
    for (int bb = 0; bb < 4; ++bb) acc[bb] = make_float4(0.f, 0.f, 0.f, 0.f);

    for (int ii = 0; ii < 36; ++ii) {
        const int i = i0 + ii;
        float4 w4[8];
        if (act) {
            const float4* wp = (const float4*)(W + (size_t)i * 1280 + q * 32);
            #pragma unroll
            for (int j = 0; j < 8; ++j) w4[j] = wp[j];
        }
        #pragma unroll
        for (int bb = 0; bb < 4; ++bb) {
            const int b = b0 + bb;
            const float4* up = (const float4*)(u + ((size_t)b * 1152 + i) * 8);
            const float4 ua = up[0], ub = up[1];
            if (act) {
                float4 uh;
                uh.x = dot8(w4[0], w4[1], ua, ub);
                uh.y = dot8(w4[2], w4[3], ua, ub);
                uh.z = dot8(w4[4], w4[5], ua, ub);
                uh.w = dot8(w4[6], w4[7], ua, ub);
                acc[bb].x += uh.x; acc[bb].y += uh.y;
                acc[bb].z += uh.z; acc[bb].w += uh.w;
                ushort4 h;
                h.x = bf16_rn(uh.x); h.y = bf16_rn(uh.y);
                h.z = bf16_rn(uh.z); h.w = bf16_rn(uh.w);
                ((ushort4*)uhat_h)[((size_t)b * 1152 + i) * UHQ + q] = h;
            }
        }
    }
    if (act) {
#if defined(__HIP_DEVICE_COMPILE__)
        #pragma unroll
        for (int bb = 0; bb < 4; ++bb) {
            float* sp = s0 + (size_t)(b0 + bb) * 160 + q * 4;
            unsafeAtomicAdd(sp + 0, acc[bb].x);
            unsafeAtomicAdd(sp + 1, acc[bb].y);
            unsafeAtomicAdd(sp + 2, acc[bb].z);
            unsafeAtomicAdd(sp + 3, acc[bb].w);
        }
#endif
    }
}

// ---------------- Routing pass v6: round-0 cd-quad kernel (VGPR ~20), full occupancy ----------------
// Wave owns (b, i-chunk); lane q = cd-quad (40/64 active). Tiny register
// footprint -> 8 waves/SIMD. Grid 2048 = 8 blocks/CU, one uniform round.
// Deltas vs round-0: K2_CH 16 (72 i/wave) and rcp for the softmax divide.
template <int PASS>
__global__ __launch_bounds__(256, 8)
void route6(const unsigned short* __restrict__ uhat_h,
            const float* __restrict__ v0g, const float* __restrict__ v1g,
            float* __restrict__ sg)
{
    const int t = threadIdx.x, lane = t & 63, wv = t >> 6;
    const int gid = blockIdx.x * 4 + wv;
    const int b   = gid >> 4;             // 0..511
    const int ch  = gid & 15;             // 0..15
    const int i0  = ch * 72;
    const int q   = lane;
    const bool act = (q < UHQ);

    float4 va = make_float4(0.f, 0.f, 0.f, 0.f);
    if (act) {
        va = ((const float4*)v0g)[(size_t)b * UHQ + q];
        if (PASS == 2) {
            const float4 vb = ((const float4*)v1g)[(size_t)b * UHQ + q];
            va.x += vb.x; va.y += vb.y; va.z += vb.z; va.w += vb.w;
        }
    }
    float4 sacc = make_float4(0.f, 0.f, 0.f, 0.f);

    const ushort4* up = (const ushort4*)uhat_h;

    for (int ii = 0; ii < 72; ii += 2) {
        const size_t qi = ((size_t)b * 1152 + i0 + ii) * UHQ + q;
        float4 uh0 = make_float4(0.f, 0.f, 0.f, 0.f);
        float4 uh1 = make_float4(0.f, 0.f, 0.f, 0.f);
        if (act) {
            const ushort4 h0 = up[qi];
            const ushort4 h1 = up[qi + UHQ];
            uh0.x = bf16_to_f(h0.x); uh0.y = bf16_to_f(h0.y);
            uh0.z = bf16_to_f(h0.z); uh0.w = bf16_to_f(h0.w);
            uh1.x = bf16_to_f(h1.x); uh1.y = bf16_to_f(h1.y);
            uh1.z = bf16_to_f(h1.z); uh1.w = bf16_to_f(h1.w);
        }
        // per-c logit: 4-lane segmented reduction (two independent chains)
        float p0 = uh0.x*va.x + uh0.y*va.y + uh0.z*va.z + uh0.w*va.w;
        float p1 = uh1.x*va.x + uh1.y*va.y + uh1.z*va.z + uh1.w*va.w;
        p0 += __shfl_xor(p0, 1);  p1 += __shfl_xor(p1, 1);
        p0 += __shfl_xor(p0, 2);  p1 += __shfl_xor(p1, 2);
        // softmax, no max-subtraction (|logit| < ~0.5); mask inactive lanes
        const float e0 = act ? __expf(p0) : 0.0f;
        const float e1 = act ? __expf(p1) : 0.0f;
        float s0v = e0, s1v = e1;
        // xor-butterfly over strides 4..32: every lane gets sum over the 10 c-groups
        s0v += __shfl_xor(s0v, 4);   s1v += __shfl_xor(s1v, 4);
        s0v += __shfl_xor(s0v, 8);   s1v += __shfl_xor(s1v, 8);
        s0v += __shfl_xor(s0v, 16);  s1v += __shfl_xor(s1v, 16);
        s0v += __shfl_xor(s0v, 32);  s1v += __shfl_xor(s1v, 32);
        const float c0 = e0 * __builtin_amdgcn_rcpf(s0v);
        const float c1 = e1 * __builtin_amdgcn_rcpf(s1v);
        sacc.x += c0 * uh0.x + c1 * uh1.x;
        sacc.y += c0 * uh0.y + c1 * uh1.y;
        sacc.z += c0 * uh0.z + c1 * uh1.z;
        sacc.w += c0 * uh0.w + c1 * uh1.w;
    }
    if (act) {
#if defined(__HIP_DEVICE_COMPILE__)
        float* sp = sg + (size_t)b * 160 + q * 4;
        unsafeAtomicAdd(sp + 0, sacc.x);
        unsafeAtomicAdd(sp + 1, sacc.y);
        unsafeAtomicAdd(sp + 2, sacc.z);
        unsafeAtomicAdd(sp + 3, sacc.w);
#endif
    }
}

// ---------------- squash with pre-scale ----------------
__global__ void squash_scale(const float* __restrict__ s, float* __restrict__ vout,
                             float scale)
{
    int r = blockIdx.x * 256 + threadIdx.x;
    if (r >= 512 * 10) return;
    const float* sp = s + (size_t)r * 16;
    float sv[16];
    float ns = 0.0f;
    #pragma unroll
    for (int d = 0; d < 16; ++d) {
        float x = sp[d] * scale;
        sv[d] = x;
        ns += x * x;
    }
    float sc = ns / ((1.0f + ns) * (sqrtf(ns) + 1e-8f));
    float* o = vout + (size_t)r * 16;
    #pragma unroll
    for (int d = 0; d < 16; ++d) o[d] = sv[d] * sc;
}

// ---------------- tiny-ws fallback (R3-style): thread owns (b,c) ----------------
template <int PASS>
__global__ __launch_bounds__(256, 4)
void pass_fb(const float* __restrict__ u, const float* __restrict__ W,
             const float* __restrict__ v0g, const float* __restrict__ v1g,
             float* __restrict__ s_atomic)
{
    const int t    = threadIdx.x;
    const int lane = t & 63;
    const int wv   = t >> 6;
    const int bsub = lane / 10;
    const int c    = lane - bsub * 10;
    const bool lane_ok = (bsub < 6);
    const int b    = blockIdx.y * 24 + wv * 6 + bsub;
    const bool valid = lane_ok && (b < 512);
    const int bc   = valid ? b : 511;
    const int base = lane_ok ? bsub * 10 : 0;
    const int i0   = blockIdx.x * 24;

    float v[16];
    #pragma unroll
    for (int d = 0; d < 16; ++d) v[d] = 0.0f;
    if (PASS >= 1) {
        const float* vp = v0g + ((size_t)bc * 10 + c) * 16;
        #pragma unroll
        for (int d = 0; d < 16; ++d) v[d] = vp[d];
        if (PASS >= 2) {
            const float* vq = v1g + ((size_t)bc * 10 + c) * 16;
            #pragma unroll
            for (int d = 0; d < 16; ++d) v[d] += vq[d];
        }
    }

    float s_acc[16];
    #pragma unroll
    for (int d = 0; d < 16; ++d) s_acc[d] = 0.0f;

    for (int ii = 0; ii < 24; ++ii) {
        const int i = i0 + ii;
        const float4* up = (const float4*)(u + ((size_t)bc * 1152 + i) * 8);
        const float4 ua = up[0];
        const float4 ub = up[1];
        const float* Wp = W + ((size_t)i * 10 + c) * 128;

        float h[16];
        #pragma unroll
        for (int d = 0; d < 16; ++d) {
            const float4* wp = (const float4*)(Wp + d * 8);
            h[d] = dot8(wp[0], wp[1], ua, ub);
        }

        if (PASS == 0) {
            #pragma unroll
            for (int d = 0; d < 16; ++d) s_acc[d] += h[d];
        } else {
            float lg = 0.0f;
            #pragma unroll
            for (int d = 0; d < 16; ++d) lg += h[d] * v[d];
            float lj[10];
            #pragma unroll
            for (int j = 0; j < 10; ++j) lj[j] = __shfl(lg, base + j);
            float m = lj[0];
            #pragma unroll
            for (int j = 1; j < 10; ++j) m = fmaxf(m, lj[j]);
            float sum = 0.0f;
            #pragma unroll
            for (int j = 0; j < 10; ++j) sum += __expf(lj[j] - m);
            const float coef = __expf(lg - m) / sum;
            #pragma unroll
            for (int d = 0; d < 16; ++d) s_acc[d] += coef * h[d];
        }
    }
    if (PASS == 0) {
        #pragma unroll
        for (int d = 0; d < 16; ++d) s_acc[d] *= 0.1f;
    }
    if (valid) {
#if defined(__HIP_DEVICE_COMPILE__)
        #pragma unroll
        for (int d = 0; d < 16; ++d)
            unsafeAtomicAdd(&s_atomic[((size_t)b * 10 + c) * 16 + d], s_acc[d]);
#endif
    }
}

extern "C" void kernel_launch(void* const* d_in, const int* in_sizes, int n_in,
                              void* d_out, int out_size, void* d_ws, size_t ws_size,
                              hipStream_t stream)
{
    const float* u = (const float*)d_in[0];   // [512,1152,8]
    const float* W = (const float*)d_in[1];   // [1152,10,16,8]
    float* out = (float*)d_out;               // [512,10,16]

    float* v0 = (float*)d_ws;
    float* v1 = v0 + 81920;
    float* s0 = v1 + 81920;
    float* s1 = s0 + 81920;
    float* s2 = s1 + 81920;
    float* wt = s2 + 81920;                   // 1,474,560 f32 (5.9 MB)

    const size_t head   = (size_t)5 * 81920 * sizeof(float);          // 1.64 MB
    const size_t wtsz   = (size_t)1152 * 1280 * sizeof(float);        // 5.90 MB
    const size_t uh_b16 = (size_t)512 * 1152 * 160 * 2;               // 188.7 MB

    hipMemsetAsync(s0, 0, (size_t)3 * 81920 * sizeof(float), stream);

    dim3 blk(256);

    if (ws_size >= head + wtsz + uh_b16) {
        unsigned short* uhh = (unsigned short*)(wt + 1152 * 1280);
        transpose_W<<<1440, blk, 0, stream>>>((const float4*)W, (float4*)wt);
        produce_uhat_t<<<1024, blk, 0, stream>>>(u, wt, uhh, s0);
        squash_scale<<<20, blk, 0, stream>>>(s0, v0, 0.1f);
        route6<1><<<2048, blk, 0, stream>>>(uhh, v0, nullptr, s1);
        squash_scale<<<20, blk, 0, stream>>>(s1, v1, 1.0f);
        route6<2><<<2048, blk, 0, stream>>>(uhh, v0, v1, s2);
        squash_scale<<<20, blk, 0, stream>>>(s2, out, 1.0f);
    } else if (ws_size >= head + uh_b16) {
        unsigned short* uhh = (unsigned short*)wt;   // no W_t buffer
        produce_uhat_div<<<1024, blk, 0, stream>>>(u, W, uhh, s0);
        squash_scale<<<20, blk, 0, stream>>>(s0, v0, 0.1f);
        route6<1><<<2048, blk, 0, stream>>>(uhh, v0, nullptr, s1);
        squash_scale<<<20, blk, 0, stream>>>(s1, v1, 1.0f);
        route6<2><<<2048, blk, 0, stream>>>(uhh, v0, v1, s2);
        squash_scale<<<20, blk, 0, stream>>>(s2, out, 1.0f);
    } else {
        dim3 grid(48, 22);
        pass_fb<0><<<grid, blk, 0, stream>>>(u, W, nullptr, nullptr, s0);
        squash_scale<<<20, blk, 0, stream>>>(s0, v0, 1.0f);
        pass_fb<1><<<grid, blk, 0, stream>>>(u, W, v0, nullptr, s1);
        squash_scale<<<20, blk, 0, stream>>>(s1, v1, 1.0f);
        pass_fb<2><<<grid, blk, 0, stream>>>(u, W, v0, v1, s2);
        squash_scale<<<20, blk, 0, stream>>>(s2, out, 1.0f);
    }
}

// Round 9
// 302.430 us; speedup vs baseline: 1.4229x; 1.0280x over previous
//
#include <hip/hip_runtime.h>
#include <math.h>

// DigitCaps dynamic routing. B=512, I=1152, K=8, C=10, D=16, 3 iters.
//
// R5 structure: materialize bf16 u_hat (189 MB) in ws; each routing pass
// streams it once; softmax fully in-register.
// R7: forcing launch_bounds below natural need -> spills. Keep (256,4).
// R10: i-split alone doubled s0 atomics: WRITE 226->268 MB = the +30us.
// R11: source-level ILP gets compiled away.
// R12: b-pairs double W_t loads: TLP gain < added work.
// R13: c-lane route family (>=80 VGPR, 4 waves/SIMD) loses to cd-quad.
// R14 WIN (311us): route6 = round-0 cd-quad route (VGPR ~20) + grid 2048
//   (8 blocks/CU uniform) + rcp. Routes ~68us/pass. Route is TLP-bound.
// R15 (this round): producer TLP decoupled from atomic cost. K1_CH 64
//   (18 i/wave) -> 8192 waves, grid 2048 = 8 blocks/CU at VGPR 64. The 4
//   waves of a block share the same b-quad -> cross-wave LDS reduction of
//   the s0 partials (7.7 KB), wave 0 alone issues atomics: 32K atomic
//   instrs (vs 65K in R9, 131K in R10). R10's TLP without its write blowup.

#define UHQ 40          // ushort4 quads per (b,i) row (160 bf16 elems)
#define K1_CH 64        // producer i-chunks (18 i each), 4 b per wave
#define K2_CH 16        // route i-chunks per b (72 i each)

__device__ __forceinline__ float dot8(const float4 w0, const float4 w1,
                                      const float4 ua, const float4 ub) {
    return w0.x*ua.x + w0.y*ua.y + w0.z*ua.z + w0.w*ua.w
         + w1.x*ub.x + w1.y*ub.y + w1.z*ub.z + w1.w*ub.w;
}

__device__ __forceinline__ unsigned short bf16_rn(float x) {
    unsigned u = __float_as_uint(x);
    u += 0x7FFFu + ((u >> 16) & 1u);
    return (unsigned short)(u >> 16);
}
__device__ __forceinline__ float bf16_to_f(unsigned short h) {
    return __uint_as_float(((unsigned)h) << 16);
}

// ---------------- W transpose: W[i][c][d][k] -> W_t[i][j][q] (float4 units) ----------------
__global__ void transpose_W(const float4* __restrict__ W4, float4* __restrict__ Wt4)
{
    int tid = blockIdx.x * 256 + threadIdx.x;
    if (tid >= 1152 * 320) return;
    int i = tid / 320, r = tid - i * 320;
    int q = r >> 3, j = r & 7;
    Wt4[i * 320 + j * 40 + q] = W4[tid];   // read coalesced, scatter within 5 KB row
}

// ---------------- Producer: u_hat bf16 + fused pass-0 sum, LDS cross-wave reduce ----------------
// K1_CH 64 -> 18 i/wave, 8192 waves, grid 2048 = 8 blocks/CU (VGPR 64 tier),
// one uniform round. Block's 4 waves share the b-quad: waves 1-3 park acc in
// LDS, wave 0 sums and does the only atomics (16 instrs/block).
__global__ __launch_bounds__(256, 4)
void produce_uhat_t(const float* __restrict__ u, const float* __restrict__ Wt,
                    unsigned short* __restrict__ uhat_h, float* __restrict__ s0)
{
    const int t = threadIdx.x, lane = t & 63, wv = t >> 6;
    const int gid = blockIdx.x * 4 + wv;
    const int bq  = gid / K1_CH;          // 0..127 (same for all 4 waves of a block)
    const int ch  = gid - bq * K1_CH;     // 0..63
    const int b0  = bq * 4;
    const int i0  = ch * 18;
    const int q   = lane;
    const bool act = (q < UHQ);

    __shared__ float4 red[480];           // 3 waves x 40 lanes x 4 float4 = 7680 B

    float4 acc[4];
    #pragma unroll
    for (int bb = 0; bb < 4; ++bb) acc[bb] = make_float4(0.f, 0.f, 0.f, 0.f);

    for (int ii = 0; ii < 18; ++ii) {
        const int i = i0 + ii;
        float4 w4[8];
        if (act) {
            const float4* wb = (const float4*)(Wt + (size_t)i * 1280);
            #pragma unroll
            for (int j = 0; j < 8; ++j) w4[j] = wb[j * 40 + q];   // 640 B contiguous
        }
        #pragma unroll
        for (int bb = 0; bb < 4; ++bb) {
            const int b = b0 + bb;
            const float4* up = (const float4*)(u + ((size_t)b * 1152 + i) * 8);
            const float4 ua = up[0], ub = up[1];   // wave-uniform broadcast
            if (act) {
                float4 uh;
                uh.x = dot8(w4[0], w4[1], ua, ub);
                uh.y = dot8(w4[2], w4[3], ua, ub);
                uh.z = dot8(w4[4], w4[5], ua, ub);
                uh.w = dot8(w4[6], w4[7], ua, ub);
                acc[bb].x += uh.x; acc[bb].y += uh.y;
                acc[bb].z += uh.z; acc[bb].w += uh.w;
                ushort4 h;
                h.x = bf16_rn(uh.x); h.y = bf16_rn(uh.y);
                h.z = bf16_rn(uh.z); h.w = bf16_rn(uh.w);
                ((ushort4*)uhat_h)[((size_t)b * 1152 + i) * UHQ + q] = h;
            }
        }
    }

    // cross-wave reduction of the pass-0 partial sums
    if (wv > 0 && act) {
        float4* rp = red + ((wv - 1) * 40 + q) * 4;
        rp[0] = acc[0]; rp[1] = acc[1]; rp[2] = acc[2]; rp[3] = acc[3];
    }
    __syncthreads();
    if (wv == 0 && act) {
        #pragma unroll
        for (int w = 0; w < 3; ++w) {
            const float4* rp = red + (w * 40 + q) * 4;
            #pragma unroll
            for (int bb = 0; bb < 4; ++bb) {
                const float4 r = rp[bb];
                acc[bb].x += r.x; acc[bb].y += r.y;
                acc[bb].z += r.z; acc[bb].w += r.w;
            }
        }
#if defined(__HIP_DEVICE_COMPILE__)
        #pragma unroll
        for (int bb = 0; bb < 4; ++bb) {
            float* sp = s0 + (size_t)(b0 + bb) * 160 + q * 4;
            unsafeAtomicAdd(sp + 0, acc[bb].x);
            unsafeAtomicAdd(sp + 1, acc[bb].y);
            unsafeAtomicAdd(sp + 2, acc[bb].z);
            unsafeAtomicAdd(sp + 3, acc[bb].w);
        }
#endif
    }
}

// ---------------- Producer fallback (divergent W, no W_t buffer; R9 geometry) ----------------
__global__ __launch_bounds__(256, 4)
void produce_uhat_div(const float* __restrict__ u, const float* __restrict__ W,
                      unsigned short* __restrict__ uhat_h, float* __restrict__ s0)
{
    const int t = threadIdx.x, lane = t & 63, wv = t >> 6;
    const int gid = blockIdx.x * 4 + wv;
    const int bq  = gid / 32;
    const int ch  = gid - bq * 32;
    const int b0  = bq * 4;
    const int i0  = ch * 36;
    const int q   = lane;
    const bool act = (q < UHQ);

    float4 acc[4];
    #pragma unroll
    for (int bb = 0; bb < 4; ++bb) acc[bb] = make_float4(0.f, 0.f, 0.f, 0.f);

    for (int ii = 0; ii < 36; ++ii) {
        const int i = i0 + ii;
        float4 w4[8];
        if (act) {
            const float4* wp = (const float4*)(W + (size_t)i * 1280 + q * 32);
            #pragma unroll
            for (int j = 0; j < 8; ++j) w4[j] = wp[j];
        }
        #pragma unroll
        for (int bb = 0; bb < 4; ++bb) {
            const int b = b0 + bb;
            const float4* up = (const float4*)(u + ((size_t)b * 1152 + i) * 8);
            const float4 ua = up[0], ub = up[1];
            if (act) {
                float4 uh;
                uh.x = dot8(w4[0], w4[1], ua, ub);
                uh.y = dot8(w4[2], w4[3], ua, ub);
                uh.z = dot8(w4[4], w4[5], ua, ub);
                uh.w = dot8(w4[6], w4[7], ua, ub);
                acc[bb].x += uh.x; acc[bb].y += uh.y;
                acc[bb].z += uh.z; acc[bb].w += uh.w;
                ushort4 h;
                h.x = bf16_rn(uh.x); h.y = bf16_rn(uh.y);
                h.z = bf16_rn(uh.z); h.w = bf16_rn(uh.w);
                ((ushort4*)uhat_h)[((size_t)b * 1152 + i) * UHQ + q] = h;
            }
        }
    }
    if (act) {
#if defined(__HIP_DEVICE_COMPILE__)
        #pragma unroll
        for (int bb = 0; bb < 4; ++bb) {
            float* sp = s0 + (size_t)(b0 + bb) * 160 + q * 4;
            unsafeAtomicAdd(sp + 0, acc[bb].x);
            unsafeAtomicAdd(sp + 1, acc[bb].y);
            unsafeAtomicAdd(sp + 2, acc[bb].z);
            unsafeAtomicAdd(sp + 3, acc[bb].w);
        }
#endif
    }
}

// ---------------- Routing pass v6: round-0 cd-quad kernel (VGPR ~20), full occupancy ----------------
// R14 WIN config: wave owns (b, i-chunk); lane q = cd-quad (40/64 active).
// Grid 2048 = 8 blocks/CU, one uniform round. rcp for the softmax divide.
template <int PASS>
__global__ __launch_bounds__(256, 8)
void route6(const unsigned short* __restrict__ uhat_h,
            const float* __restrict__ v0g, const float* __restrict__ v1g,
            float* __restrict__ sg)
{
    const int t = threadIdx.x, lane = t & 63, wv = t >> 6;
    const int gid = blockIdx.x * 4 + wv;
    const int b   = gid >> 4;             // 0..511
    const int ch  = gid & 15;             // 0..15
    const int i0  = ch * 72;
    const int q   = lane;
    const bool act = (q < UHQ);

    float4 va = make_float4(0.f, 0.f, 0.f, 0.f);
    if (act) {
        va = ((const float4*)v0g)[(size_t)b * UHQ + q];
        if (PASS == 2) {
            const float4 vb = ((const float4*)v1g)[(size_t)b * UHQ + q];
            va.x += vb.x; va.y += vb.y; va.z += vb.z; va.w += vb.w;
        }
    }
    float4 sacc = make_float4(0.f, 0.f, 0.f, 0.f);

    const ushort4* up = (const ushort4*)uhat_h;

    for (int ii = 0; ii < 72; ii += 2) {
        const size_t qi = ((size_t)b * 1152 + i0 + ii) * UHQ + q;
        float4 uh0 = make_float4(0.f, 0.f, 0.f, 0.f);
        float4 uh1 = make_float4(0.f, 0.f, 0.f, 0.f);
        if (act) {
            const ushort4 h0 = up[qi];
            const ushort4 h1 = up[qi + UHQ];
            uh0.x = bf16_to_f(h0.x); uh0.y = bf16_to_f(h0.y);
            uh0.z = bf16_to_f(h0.z); uh0.w = bf16_to_f(h0.w);
            uh1.x = bf16_to_f(h1.x); uh1.y = bf16_to_f(h1.y);
            uh1.z = bf16_to_f(h1.z); uh1.w = bf16_to_f(h1.w);
        }
        // per-c logit: 4-lane segmented reduction (two independent chains)
        float p0 = uh0.x*va.x + uh0.y*va.y + uh0.z*va.z + uh0.w*va.w;
        float p1 = uh1.x*va.x + uh1.y*va.y + uh1.z*va.z + uh1.w*va.w;
        p0 += __shfl_xor(p0, 1);  p1 += __shfl_xor(p1, 1);
        p0 += __shfl_xor(p0, 2);  p1 += __shfl_xor(p1, 2);
        // softmax, no max-subtraction (|logit| < ~0.5); mask inactive lanes
        const float e0 = act ? __expf(p0) : 0.0f;
        const float e1 = act ? __expf(p1) : 0.0f;
        float s0v = e0, s1v = e1;
        // xor-butterfly over strides 4..32: every lane gets sum over the 10 c-groups
        s0v += __shfl_xor(s0v, 4);   s1v += __shfl_xor(s1v, 4);
        s0v += __shfl_xor(s0v, 8);   s1v += __shfl_xor(s1v, 8);
        s0v += __shfl_xor(s0v, 16);  s1v += __shfl_xor(s1v, 16);
        s0v += __shfl_xor(s0v, 32);  s1v += __shfl_xor(s1v, 32);
        const float c0 = e0 * __builtin_amdgcn_rcpf(s0v);
        const float c1 = e1 * __builtin_amdgcn_rcpf(s1v);
        sacc.x += c0 * uh0.x + c1 * uh1.x;
        sacc.y += c0 * uh0.y + c1 * uh1.y;
        sacc.z += c0 * uh0.z + c1 * uh1.z;
        sacc.w += c0 * uh0.w + c1 * uh1.w;
    }
    if (act) {
#if defined(__HIP_DEVICE_COMPILE__)
        float* sp = sg + (size_t)b * 160 + q * 4;
        unsafeAtomicAdd(sp + 0, sacc.x);
        unsafeAtomicAdd(sp + 1, sacc.y);
        unsafeAtomicAdd(sp + 2, sacc.z);
        unsafeAtomicAdd(sp + 3, sacc.w);
#endif
    }
}

// ---------------- squash with pre-scale ----------------
__global__ void squash_scale(const float* __restrict__ s, float* __restrict__ vout,
                             float scale)
{
    int r = blockIdx.x * 256 + threadIdx.x;
    if (r >= 512 * 10) return;
    const float* sp = s + (size_t)r * 16;
    float sv[16];
    float ns = 0.0f;
    #pragma unroll
    for (int d = 0; d < 16; ++d) {
        float x = sp[d] * scale;
        sv[d] = x;
        ns += x * x;
    }
    float sc = ns / ((1.0f + ns) * (sqrtf(ns) + 1e-8f));
    float* o = vout + (size_t)r * 16;
    #pragma unroll
    for (int d = 0; d < 16; ++d) o[d] = sv[d] * sc;
}

// ---------------- tiny-ws fallback (R3-style): thread owns (b,c) ----------------
template <int PASS>
__global__ __launch_bounds__(256, 4)
void pass_fb(const float* __restrict__ u, const float* __restrict__ W,
             const float* __restrict__ v0g, const float* __restrict__ v1g,
             float* __restrict__ s_atomic)
{
    const int t    = threadIdx.x;
    const int lane = t & 63;
    const int wv   = t >> 6;
    const int bsub = lane / 10;
    const int c    = lane - bsub * 10;
    const bool lane_ok = (bsub < 6);
    const int b    = blockIdx.y * 24 + wv * 6 + bsub;
    const bool valid = lane_ok && (b < 512);
    const int bc   = valid ? b : 511;
    const int base = lane_ok ? bsub * 10 : 0;
    const int i0   = blockIdx.x * 24;

    float v[16];
    #pragma unroll
    for (int d = 0; d < 16; ++d) v[d] = 0.0f;
    if (PASS >= 1) {
        const float* vp = v0g + ((size_t)bc * 10 + c) * 16;
        #pragma unroll
        for (int d = 0; d < 16; ++d) v[d] = vp[d];
        if (PASS >= 2) {
            const float* vq = v1g + ((size_t)bc * 10 + c) * 16;
            #pragma unroll
            for (int d = 0; d < 16; ++d) v[d] += vq[d];
        }
    }

    float s_acc[16];
    #pragma unroll
    for (int d = 0; d < 16; ++d) s_acc[d] = 0.0f;

    for (int ii = 0; ii < 24; ++ii) {
        const int i = i0 + ii;
        const float4* up = (const float4*)(u + ((size_t)bc * 1152 + i) * 8);
        const float4 ua = up[0];
        const float4 ub = up[1];
        const float* Wp = W + ((size_t)i * 10 + c) * 128;

        float h[16];
        #pragma unroll
        for (int d = 0; d < 16; ++d) {
            const float4* wp = (const float4*)(Wp + d * 8);
            h[d] = dot8(wp[0], wp[1], ua, ub);
        }

        if (PASS == 0) {
            #pragma unroll
            for (int d = 0; d < 16; ++d) s_acc[d] += h[d];
        } else {
            float lg = 0.0f;
            #pragma unroll
            for (int d = 0; d < 16; ++d) lg += h[d] * v[d];
            float lj[10];
            #pragma unroll
            for (int j = 0; j < 10; ++j) lj[j] = __shfl(lg, base + j);
            float m = lj[0];
            #pragma unroll
            for (int j = 1; j < 10; ++j) m = fmaxf(m, lj[j]);
            float sum = 0.0f;
            #pragma unroll
            for (int j = 0; j < 10; ++j) sum += __expf(lj[j] - m);
            const float coef = __expf(lg - m) / sum;
            #pragma unroll
            for (int d = 0; d < 16; ++d) s_acc[d] += coef * h[d];
        }
    }
    if (PASS == 0) {
        #pragma unroll
        for (int d = 0; d < 16; ++d) s_acc[d] *= 0.1f;
    }
    if (valid) {
#if defined(__HIP_DEVICE_COMPILE__)
        #pragma unroll
        for (int d = 0; d < 16; ++d)
            unsafeAtomicAdd(&s_atomic[((size_t)b * 10 + c) * 16 + d], s_acc[d]);
#endif
    }
}

extern "C" void kernel_launch(void* const* d_in, const int* in_sizes, int n_in,
                              void* d_out, int out_size, void* d_ws, size_t ws_size,
                              hipStream_t stream)
{
    const float* u = (const float*)d_in[0];   // [512,1152,8]
    const float* W = (const float*)d_in[1];   // [1152,10,16,8]
    float* out = (float*)d_out;               // [512,10,16]

    float* v0 = (float*)d_ws;
    float* v1 = v0 + 81920;
    float* s0 = v1 + 81920;
    float* s1 = s0 + 81920;
    float* s2 = s1 + 81920;
    float* wt = s2 + 81920;                   // 1,474,560 f32 (5.9 MB)

    const size_t head   = (size_t)5 * 81920 * sizeof(float);          // 1.64 MB
    const size_t wtsz   = (size_t)1152 * 1280 * sizeof(float);        // 5.90 MB
    const size_t uh_b16 = (size_t)512 * 1152 * 160 * 2;               // 188.7 MB

    hipMemsetAsync(s0, 0, (size_t)3 * 81920 * sizeof(float), stream);

    dim3 blk(256);

    if (ws_size >= head + wtsz + uh_b16) {
        unsigned short* uhh = (unsigned short*)(wt + 1152 * 1280);
        transpose_W<<<1440, blk, 0, stream>>>((const float4*)W, (float4*)wt);
        produce_uhat_t<<<2048, blk, 0, stream>>>(u, wt, uhh, s0);
        squash_scale<<<20, blk, 0, stream>>>(s0, v0, 0.1f);
        route6<1><<<2048, blk, 0, stream>>>(uhh, v0, nullptr, s1);
        squash_scale<<<20, blk, 0, stream>>>(s1, v1, 1.0f);
        route6<2><<<2048, blk, 0, stream>>>(uhh, v0, v1, s2);
        squash_scale<<<20, blk, 0, stream>>>(s2, out, 1.0f);
    } else if (ws_size >= head + uh_b16) {
        unsigned short* uhh = (unsigned short*)wt;   // no W_t buffer
        produce_uhat_div<<<1024, blk, 0, stream>>>(u, W, uhh, s0);
        squash_scale<<<20, blk, 0, stream>>>(s0, v0, 0.1f);
        route6<1><<<2048, blk, 0, stream>>>(uhh, v0, nullptr, s1);
        squash_scale<<<20, blk, 0, stream>>>(s1, v1, 1.0f);
        route6<2><<<2048, blk, 0, stream>>>(uhh, v0, v1, s2);
        squash_scale<<<20, blk, 0, stream>>>(s2, out, 1.0f);
    } else {
        dim3 grid(48, 22);
        pass_fb<0><<<grid, blk, 0, stream>>>(u, W, nullptr, nullptr, s0);
        squash_scale<<<20, blk, 0, stream>>>(s0, v0, 1.0f);
        pass_fb<1><<<grid, blk, 0, stream>>>(u, W, v0, nullptr, s1);
        squash_scale<<<20, blk, 0, stream>>>(s1, v1, 1.0f);
        pass_fb<2><<<grid, blk, 0, stream>>>(u, W, v0, v1, s2);
        squash_scale<<<20, blk, 0, stream>>>(s2, out, 1.0f);
    }
}